// Round 3
// baseline (9502.638 us; speedup 1.0000x reference)
//
#include <hip/hip_runtime.h>
#include <cstdint>

// ---------------- problem constants (fixed by setup_inputs) ----------------
#define PIX_TOTAL 87296          // sum of H*W over 5 levels (per image)
#define ATOT      261888        // PIX_TOTAL * 3 anchors
#define PS        2618880       // 2 images * PIX_TOTAL * 15 outputs (per cb partial)
#define MTOT      4768          // 1000*4 + 768 concat length per image
#define SCALE_CLAMP 4.135166556742356f
#define WSTR      65            // padded w_lds stride (bank-conflict fix)

__device__ __forceinline__ unsigned fmono(float f) {
  unsigned u = __float_as_uint(f);
  return (u & 0x80000000u) ? ~u : (u | 0x80000000u);
}
__device__ __forceinline__ int lvl_pxb(int l) {
  switch (l) { case 0: return 0; case 1: return 65536; case 2: return 81920;
               case 3: return 86016; default: return 87040; }
}

// ---------------------------------------------------------------------------
// Kernel 1: 3x3 conv (C=256->256) + bias + ReLU, fused 1x1 obj(3)/delta(12)
// partial dot-products over this block's 64 output channels.
// Thread shape: 8 oc x PXT px (64 accs at PXT=8) -> 48 B LDS per FMA-instr,
// under the ~112 B/cyc/CU LDS ceiling => compute-bound on the fp32 VALU.
// Block: 512 thr = 8 oc-groups x 64 px-groups. Grid: (tiles, 4 cblk, 2 img).
// Deterministic partials (no atomics).
// ---------------------------------------------------------------------------
template<int TW, int TH, int PXT>
__global__ void __launch_bounds__(512, 4)
conv3_fused(const float* __restrict__ feat, const float* __restrict__ cw,
            const float* __restrict__ cbias, const float* __restrict__ ow,
            const float* __restrict__ dw, float* __restrict__ partial,
            int H, int W, int px_base)
{
  constexpr int SR    = TW + 4;          // padded LDS row stride (mult of 4)
  constexpr int ROWSZ = (TH + 2) * SR;
  constexpr int IN_N  = 8 * ROWSZ;
  constexpr int NR    = PXT / 4 + 1;     // float4 window reads per row

  const int tid  = threadIdx.x;
  const int tc   = tid & 7;              // 8 output channels each
  const int tp   = tid >> 3;             // pixel group (PXT px each)
  const int cblk = blockIdx.y;
  const int img  = blockIdx.z;
  const int tilesx = W / TW;
  const int ty = blockIdx.x / tilesx;
  const int tx = blockIdx.x - ty * tilesx;
  const int y0 = ty * TH, x0 = tx * TW;
  const int p  = tp * PXT;
  const int py = p / TW, px = p % TW;    // PXT consecutive px in one row

  __shared__ __align__(16) float in_lds[IN_N];
  __shared__ __align__(16) float w_lds[8 * 9 * WSTR];
  __shared__ __align__(16) float wo_lds[15 * 64];

  // obj/delta weights for this block's 64 channels
  for (int l = tid; l < 960; l += 512) {
    int o = l >> 6, c = l & 63;
    int cg = cblk * 64 + c;
    wo_lds[l] = (o < 3) ? ow[o * 256 + cg] : dw[(o - 3) * 256 + cg];
  }

  float acc[PXT][8];
  #pragma unroll
  for (int j = 0; j < PXT; ++j)
    #pragma unroll
    for (int c = 0; c < 8; ++c) acc[j][c] = 0.f;

  const float* fbase = feat + (size_t)img * 256 * H * W;

  for (int c0 = 0; c0 < 256; c0 += 8) {
    __syncthreads();
    // stage input tile (+1 halo all around, zero padded)
    for (int l = tid; l < IN_N; l += 512) {
      int ci  = l / ROWSZ;
      int rem = l - ci * ROWSZ;
      int yy  = rem / SR, xx = rem - yy * SR;
      int gy = y0 - 1 + yy, gx = x0 - 1 + xx;
      float v = 0.f;
      if (gy >= 0 && gy < H && gx >= 0 && gx < W)
        v = fbase[((c0 + ci) * H + gy) * W + gx];
      in_lds[l] = v;
    }
    // stage weights: 4608 vals = 512 threads * 9 contiguous floats
    {
      int oc = tid >> 3, ci = tid & 7;
      const float* wp = cw + ((size_t)(cblk * 64 + oc) * 256 + (c0 + ci)) * 9;
      #pragma unroll
      for (int tap = 0; tap < 9; ++tap)
        w_lds[(ci * 9 + tap) * WSTR + oc] = wp[tap];
    }
    __syncthreads();
    for (int ci = 0; ci < 8; ++ci) {
      #pragma unroll
      for (int ky = 0; ky < 3; ++ky) {
        const float* row = &in_lds[(ci * (TH + 2) + py + ky) * SR + px];
        float win[4 * NR];
        #pragma unroll
        for (int rr = 0; rr < NR; ++rr) {
          float4 rv = *(const float4*)(row + 4 * rr);
          win[4*rr+0] = rv.x; win[4*rr+1] = rv.y;
          win[4*rr+2] = rv.z; win[4*rr+3] = rv.w;
        }
        #pragma unroll
        for (int kx = 0; kx < 3; ++kx) {
          const float* wb = &w_lds[(ci * 9 + ky * 3 + kx) * WSTR + tc * 8];
          float4 w0 = *(const float4*)wb;
          float4 w1 = *(const float4*)(wb + 4);
          #pragma unroll
          for (int j = 0; j < PXT; ++j) {
            float bv = win[j + kx];
            acc[j][0] = fmaf(bv, w0.x, acc[j][0]);
            acc[j][1] = fmaf(bv, w0.y, acc[j][1]);
            acc[j][2] = fmaf(bv, w0.z, acc[j][2]);
            acc[j][3] = fmaf(bv, w0.w, acc[j][3]);
            acc[j][4] = fmaf(bv, w1.x, acc[j][4]);
            acc[j][5] = fmaf(bv, w1.y, acc[j][5]);
            acc[j][6] = fmaf(bv, w1.z, acc[j][6]);
            acc[j][7] = fmaf(bv, w1.w, acc[j][7]);
          }
        }
      }
    }
  }

  // epilogue: t = relu(acc + bias); partial obj/delta dots over 64 ch
  float tv[PXT][8];
  #pragma unroll
  for (int c = 0; c < 8; ++c) {
    float b = cbias[cblk * 64 + tc * 8 + c];
    #pragma unroll
    for (int j = 0; j < PXT; ++j) tv[j][c] = fmaxf(acc[j][c] + b, 0.f);
  }
  const int gy = y0 + py;
  const int gx0 = x0 + px;
  const size_t pbase = (size_t)cblk * PS +
      ((size_t)img * PIX_TOTAL + px_base + gy * W + gx0) * 15;
  for (int o = 0; o < 15; ++o) {
    const float* wb = &wo_lds[o * 64 + tc * 8];
    float4 w0 = *(const float4*)wb;
    float4 w1 = *(const float4*)(wb + 4);
    float s[PXT];
    #pragma unroll
    for (int j = 0; j < PXT; ++j)
      s[j] = tv[j][0]*w0.x + tv[j][1]*w0.y + tv[j][2]*w0.z + tv[j][3]*w0.w
           + tv[j][4]*w1.x + tv[j][5]*w1.y + tv[j][6]*w1.z + tv[j][7]*w1.w;
    #pragma unroll
    for (int m = 1; m < 8; m <<= 1) {
      #pragma unroll
      for (int j = 0; j < PXT; ++j) s[j] += __shfl_xor(s[j], m, 64);
    }
    if (tc == 0) {
      #pragma unroll
      for (int j = 0; j < PXT; ++j)
        partial[pbase + (size_t)j * 15 + o] = s[j];
    }
  }
}

// ---------------------------------------------------------------------------
// Kernel 2: deterministic reduce of 4 channel-block partials + bias.
// ---------------------------------------------------------------------------
__global__ void __launch_bounds__(256)
reduce_kernel(const float* __restrict__ partial, const float* __restrict__ ob,
              const float* __restrict__ db, float* __restrict__ scores,
              float* __restrict__ deltas)
{
  int v = blockIdx.x * 256 + threadIdx.x;
  if (v >= PS) return;
  float s = ((partial[v] + partial[(size_t)PS + v]) + partial[(size_t)2 * PS + v])
            + partial[(size_t)3 * PS + v];
  int o = v % 15;
  int pv = v / 15;                       // img*PIX_TOTAL + pixel
  if (o < 3) {
    scores[(size_t)pv * 3 + o] = s + ob[o];
  } else {
    int c = o - 3;                       // a*4 + d
    deltas[((size_t)pv * 3 + (c >> 2)) * 4 + (c & 3)] = s + db[c];
  }
}

// ---------------------------------------------------------------------------
// Kernel 3: per-(img,lvl) exact top-k (radix select on monotone bits, tie
// break = lowest anchor index, matching jax.lax.top_k), then bitonic sort
// by (score desc, idx asc).
// ---------------------------------------------------------------------------
__global__ void __launch_bounds__(1024)
topk_kernel(const float* __restrict__ scores, float* __restrict__ sel_s,
            unsigned* __restrict__ sel_i)
{
  const int tid = threadIdx.x;
  const int bid = blockIdx.x;            // img*5 + lvl
  const int img = bid / 5, lvl = bid % 5;
  const int W = 256 >> lvl;
  const int N = W * W * 3;
  const int k = N < 1000 ? N : 1000;
  const float* sc = scores + (size_t)img * ATOT + (size_t)lvl_pxb(lvl) * 3;

  __shared__ unsigned hist[256];
  __shared__ unsigned sh_pref, sh_want;
  __shared__ int cnt_gt, cnt_tie;
  __shared__ float ss[1024];
  __shared__ unsigned si[1024];
  __shared__ unsigned ties[2048];

  unsigned prefix = 0; unsigned want = (unsigned)k;
  for (int pass = 0; pass < 4; ++pass) {
    const int shift = 24 - 8 * pass;
    if (tid < 256) hist[tid] = 0;
    __syncthreads();
    for (int i = tid; i < N; i += 1024) {
      unsigned u = fmono(sc[i]);
      if (pass == 0 || (u >> (shift + 8)) == prefix)
        atomicAdd(&hist[(u >> shift) & 255u], 1u);
    }
    __syncthreads();
    if (tid == 0) {
      unsigned cum = 0; int b = 255;
      for (; b > 0; --b) {
        if (cum + hist[b] >= want) break;
        cum += hist[b];
      }
      sh_pref = (prefix << 8) | (unsigned)b;
      sh_want = want - cum;
    }
    __syncthreads();
    prefix = sh_pref; want = sh_want;
    __syncthreads();
  }
  const unsigned T = prefix;             // exact 32-bit k-th key

  ss[tid] = -3e38f; si[tid] = 0xFFFFFFFFu;
  if (tid == 0) { cnt_gt = 0; cnt_tie = 0; }
  __syncthreads();
  for (int i = tid; i < N; i += 1024) {
    float f = sc[i];
    unsigned u = fmono(f);
    if (u > T) {
      int pos = atomicAdd(&cnt_gt, 1);
      ss[pos] = f; si[pos] = (unsigned)i;
    } else if (u == T) {
      int pos = atomicAdd(&cnt_tie, 1);
      if (pos < 2048) ties[pos] = (unsigned)i;
    }
  }
  __syncthreads();
  const int cg = cnt_gt;
  int need = k - cg;
  const int tn = cnt_tie < 2048 ? cnt_tie : 2048;
  if (need > tn) need = tn;              // pathological overflow guard
  for (int e = tid; e < tn; e += 1024) {
    unsigned mye = ties[e];
    int rank = 0;
    for (int j = 0; j < tn; ++j) rank += (ties[j] < mye) ? 1 : 0;
    if (rank < need) { ss[cg + rank] = sc[mye]; si[cg + rank] = mye; }
  }
  __syncthreads();
  // bitonic sort, descending by (score, idx asc); composite keys unique
  for (int k2 = 2; k2 <= 1024; k2 <<= 1) {
    for (int j2 = k2 >> 1; j2 > 0; j2 >>= 1) {
      int l2 = tid ^ j2;
      if (l2 > tid) {
        float a = ss[tid], b = ss[l2];
        unsigned ia = si[tid], ib = si[l2];
        bool less = (a < b) || (a == b && ia > ib);
        bool up = ((tid & k2) == 0);
        if (less == up) { ss[tid] = b; ss[l2] = a; si[tid] = ib; si[l2] = ia; }
      }
      __syncthreads();
    }
  }
  sel_s[(size_t)bid * 1024 + tid] = ss[tid];
  sel_i[(size_t)bid * 1024 + tid] = si[tid];
}

// ---------------------------------------------------------------------------
// Kernel 4: anchor + delta decode + clip (contraction-free to match numpy),
// raw boxes for output, offset boxes (+lvl*4096, quantizing!) for NMS.
// ---------------------------------------------------------------------------
__global__ void __launch_bounds__(256)
decode_kernel(const unsigned* __restrict__ sel_i, const float* __restrict__ deltas,
              float* __restrict__ braw, float* __restrict__ boff)
{
  int g = blockIdx.x * 256 + threadIdx.x;
  if (g >= 10240) return;
  int bid = g >> 10, r = g & 1023;
  int img = bid / 5, lvl = bid % 5;
  int W = 256 >> lvl, N = W * W * 3;
  int k = N < 1000 ? N : 1000;
  if (r >= k) return;
  unsigned idx = sel_i[(size_t)bid * 1024 + r];
  float obx[4] = {0.f, 0.f, 0.f, 0.f};
  if (idx < (unsigned)N) {
    int a = idx % 3;
    int pix = idx / 3;
    int x = pix % W, y = pix / W;
    float ar = (a == 0) ? 0.5f : (a == 1 ? 1.0f : 2.0f);
    float sz = (float)(32 << lvl);
    float stridef = (float)(4 << lvl);
    float wa0 = __fdiv_rn(sz, __fsqrt_rn(ar));
    float ha0 = __fmul_rn(wa0, ar);
    float sx = __fmul_rn((float)x, stridef);   // exact
    float sy = __fmul_rn((float)y, stridef);
    float x1a = __fadd_rn(sx, -0.5f * wa0);
    float y1a = __fadd_rn(sy, -0.5f * ha0);
    float x2a = __fadd_rn(sx,  0.5f * wa0);
    float y2a = __fadd_rn(sy,  0.5f * ha0);
    float wa  = __fsub_rn(x2a, x1a);
    float ha  = __fsub_rn(y2a, y1a);
    float cxa = __fadd_rn(x1a, __fmul_rn(0.5f, wa));
    float cya = __fadd_rn(y1a, __fmul_rn(0.5f, ha));
    const float* dl = deltas + ((size_t)img * ATOT + (size_t)lvl_pxb(lvl) * 3 + idx) * 4;
    float dx = dl[0], dy = dl[1];
    float dwv = fminf(dl[2], SCALE_CLAMP);
    float dhv = fminf(dl[3], SCALE_CLAMP);
    float cx = __fadd_rn(__fmul_rn(dx, wa), cxa);
    float cy = __fadd_rn(__fmul_rn(dy, ha), cya);
    float wb = __fmul_rn(expf(dwv), wa);
    float hb = __fmul_rn(expf(dhv), ha);
    obx[0] = fminf(fmaxf(__fsub_rn(cx, __fmul_rn(0.5f, wb)), 0.f), 1024.f);
    obx[1] = fminf(fmaxf(__fsub_rn(cy, __fmul_rn(0.5f, hb)), 0.f), 1024.f);
    obx[2] = fminf(fmaxf(__fadd_rn(cx, __fmul_rn(0.5f, wb)), 0.f), 1024.f);
    obx[3] = fminf(fmaxf(__fadd_rn(cy, __fmul_rn(0.5f, hb)), 0.f), 1024.f);
  }
  float loff = (float)lvl * 4096.0f;
  size_t o = ((size_t)bid * 1024 + r) * 4;
  braw[o + 0] = obx[0]; braw[o + 1] = obx[1];
  braw[o + 2] = obx[2]; braw[o + 3] = obx[3];
  boff[o + 0] = __fadd_rn(obx[0], loff); boff[o + 1] = __fadd_rn(obx[1], loff);
  boff[o + 2] = __fadd_rn(obx[2], loff); boff[o + 3] = __fadd_rn(obx[3], loff);
}

// ---------------------------------------------------------------------------
// Kernel 5: per-(img,lvl) greedy NMS on offset boxes (cross-level IoU is
// exactly 0 thanks to +4096*lvl, so per-level == global NMS).
// ---------------------------------------------------------------------------
__global__ void __launch_bounds__(256)
nms_kernel(const float* __restrict__ boff, unsigned* __restrict__ sup_out)
{
  const int bid = blockIdx.x;
  const int lvl = bid % 5;
  const int W = 256 >> lvl;
  const int N = W * W * 3;
  const int k = N < 1000 ? N : 1000;
  const int tid = threadIdx.x;
  __shared__ float bx1[1000], by1[1000], bx2[1000], by2[1000], bar_[1000];
  __shared__ int sup[1000];
  for (int i = tid; i < k; i += 256) {
    const float* b = boff + ((size_t)bid * 1024 + i) * 4;
    float x1 = b[0], y1 = b[1], x2 = b[2], y2 = b[3];
    bx1[i] = x1; by1[i] = y1; bx2[i] = x2; by2[i] = y2;
    bar_[i] = __fmul_rn(__fsub_rn(x2, x1), __fsub_rn(y2, y1));
    sup[i] = 0;
  }
  __syncthreads();
  for (int i = 0; i < k - 1; ++i) {
    if (!sup[i]) {
      float xi1 = bx1[i], yi1 = by1[i], xi2 = bx2[i], yi2 = by2[i], ai = bar_[i];
      for (int j = i + 1 + tid; j < k; j += 256) {
        if (sup[j]) continue;
        float lx = fmaxf(xi1, bx1[j]);
        float ly = fmaxf(yi1, by1[j]);
        float rx = fminf(xi2, bx2[j]);
        float ry = fminf(yi2, by2[j]);
        float w2 = fmaxf(__fsub_rn(rx, lx), 0.f);
        float h2 = fmaxf(__fsub_rn(ry, ly), 0.f);
        float inter = __fmul_rn(w2, h2);
        float den = __fadd_rn(__fsub_rn(__fadd_rn(ai, bar_[j]), inter), 1e-9f);
        if (__fdiv_rn(inter, den) > 0.7f) sup[j] = 1;
      }
    }
    __syncthreads();
  }
  for (int i = tid; i < k; i += 256) sup_out[(size_t)bid * 1024 + i] = (unsigned)sup[i];
}

// ---------------------------------------------------------------------------
// Kernel 6: replicate top_k(masked, 1000) by rank counting over the 4768
// concatenated entries (ties: lower concat idx first == stable argsort).
// ---------------------------------------------------------------------------
__global__ void __launch_bounds__(1024)
merge_kernel(const float* __restrict__ sel_s, const unsigned* __restrict__ sup,
             const float* __restrict__ braw, float* __restrict__ out)
{
  const int img = blockIdx.x;
  const int tid = threadIdx.x;
  __shared__ float ms[MTOT];
  for (int e = tid; e < MTOT; e += 1024) {
    int lvl = e < 4000 ? e / 1000 : 4;
    int r = e - lvl * 1000;
    size_t p2 = (size_t)(img * 5 + lvl) * 1024 + r;
    ms[e] = sup[p2] ? -1e9f : sel_s[p2];
  }
  __syncthreads();
  for (int e = tid; e < MTOT; e += 1024) {
    float me = ms[e];
    int rank = 0;
    for (int j = 0; j < MTOT; ++j) {
      float mj = ms[j];
      rank += (mj > me || (mj == me && j < e)) ? 1 : 0;
    }
    if (rank < 1000) {
      int lvl = e < 4000 ? e / 1000 : 4;
      int r = e - lvl * 1000;
      const float* b = braw + ((size_t)(img * 5 + lvl) * 1024 + r) * 4;
      float* o = out + ((size_t)img * 1000 + rank) * 5;
      o[0] = b[0]; o[1] = b[1]; o[2] = b[2]; o[3] = b[3]; o[4] = me;
    }
  }
}

// ---------------------------------------------------------------------------
extern "C" void kernel_launch(void* const* d_in, const int* in_sizes, int n_in,
                              void* d_out, int out_size, void* d_ws, size_t ws_size,
                              hipStream_t stream)
{
  const float* f0 = (const float*)d_in[0];
  const float* f1 = (const float*)d_in[1];
  const float* f2 = (const float*)d_in[2];
  const float* f3 = (const float*)d_in[3];
  const float* f4 = (const float*)d_in[4];
  const float* cw = (const float*)d_in[5];
  const float* cb = (const float*)d_in[6];
  const float* ow = (const float*)d_in[7];
  const float* ob = (const float*)d_in[8];
  const float* dw = (const float*)d_in[9];
  const float* db = (const float*)d_in[10];
  float* out = (float*)d_out;

  float* ws       = (float*)d_ws;
  float* partial  = ws;                              // 4*PS = 10,475,520 f
  float* scores   = ws + (size_t)4 * PS;             // 2*ATOT = 523,776 f
  float* deltas   = scores + (size_t)2 * ATOT;       // 8*ATOT = 2,095,104 f
  float* sel_s    = deltas + (size_t)8 * ATOT;       // 10,240 f
  unsigned* sel_i = (unsigned*)(sel_s + 10240);      // 10,240 u32
  float* braw     = (float*)(sel_i + 10240);         // 40,960 f
  float* boff     = braw + 40960;                    // 40,960 f
  unsigned* sup   = (unsigned*)(boff + 40960);       // 10,240 u32

  conv3_fused<128, 4, 8><<<dim3(128, 4, 2), 512, 0, stream>>>(f0, cw, cb, ow, dw, partial, 256, 256, 0);
  conv3_fused<128, 4, 8><<<dim3( 32, 4, 2), 512, 0, stream>>>(f1, cw, cb, ow, dw, partial, 128, 128, 65536);
  conv3_fused< 64, 8, 8><<<dim3(  8, 4, 2), 512, 0, stream>>>(f2, cw, cb, ow, dw, partial,  64,  64, 81920);
  conv3_fused< 32,16, 8><<<dim3(  2, 4, 2), 512, 0, stream>>>(f3, cw, cb, ow, dw, partial,  32,  32, 86016);
  conv3_fused< 16,16, 4><<<dim3(  1, 4, 2), 512, 0, stream>>>(f4, cw, cb, ow, dw, partial,  16,  16, 87040);
  reduce_kernel<<<PS / 256, 256, 0, stream>>>(partial, ob, db, scores, deltas);
  topk_kernel<<<10, 1024, 0, stream>>>(scores, sel_s, sel_i);
  decode_kernel<<<40, 256, 0, stream>>>(sel_i, deltas, braw, boff);
  nms_kernel<<<10, 256, 0, stream>>>(boff, sup);
  merge_kernel<<<2, 1024, 0, stream>>>(sel_s, sup, braw, out);
}

// Round 4
// 9274.652 us; speedup vs baseline: 1.0246x; 1.0246x over previous
//
#include <hip/hip_runtime.h>
#include <cstdint>

// ---------------- problem constants (fixed by setup_inputs) ----------------
#define PIX_TOTAL 87296          // sum of H*W over 5 levels (per image)
#define ATOT      261888        // PIX_TOTAL * 3 anchors
#define PS        2618880       // 2 images * PIX_TOTAL * 15 outputs (per cb partial)
#define MTOT      4768          // 1000*4 + 768 concat length per image
#define SCALE_CLAMP 4.135166556742356f
#define WSTR      65            // padded w_lds stride (bank-conflict fix)
#define NW        16            // 64-bit words per NMS suppression row

__device__ __forceinline__ unsigned fmono(float f) {
  unsigned u = __float_as_uint(f);
  return (u & 0x80000000u) ? ~u : (u | 0x80000000u);
}
__device__ __forceinline__ int lvl_pxb(int l) {
  switch (l) { case 0: return 0; case 1: return 65536; case 2: return 81920;
               case 3: return 86016; default: return 87040; }
}

// ---------------------------------------------------------------------------
// Kernel 1: 3x3 conv (C=256->256) + bias + ReLU, fused 1x1 obj(3)/delta(12)
// partial dot-products over this block's 64 output channels.
// Thread shape: 8 oc x PXT px (64 accs at PXT=8).
// NOTE: __launch_bounds__(512) ONLY — round-3's (512,4) capped arch-VGPRs at
// 64 (measured VGPR_Count=64) and forced the acc tile out of registers
// (3851us, VALUBusy 34%). ~110 VGPR -> 2 blocks/CU is the intended point.
// ---------------------------------------------------------------------------
template<int TW, int TH, int PXT>
__global__ void __launch_bounds__(512)
conv3_fused(const float* __restrict__ feat, const float* __restrict__ cw,
            const float* __restrict__ cbias, const float* __restrict__ ow,
            const float* __restrict__ dw, float* __restrict__ partial,
            int H, int W, int px_base)
{
  constexpr int SR    = TW + 4;          // padded LDS row stride (mult of 4)
  constexpr int ROWSZ = (TH + 2) * SR;
  constexpr int IN_N  = 8 * ROWSZ;
  constexpr int NR    = PXT / 4 + 1;     // float4 window reads per row

  const int tid  = threadIdx.x;
  const int tc   = tid & 7;              // 8 output channels each
  const int tp   = tid >> 3;             // pixel group (PXT px each)
  const int cblk = blockIdx.y;
  const int img  = blockIdx.z;
  const int tilesx = W / TW;
  const int ty = blockIdx.x / tilesx;
  const int tx = blockIdx.x - ty * tilesx;
  const int y0 = ty * TH, x0 = tx * TW;
  const int p  = tp * PXT;
  const int py = p / TW, px = p % TW;    // PXT consecutive px in one row

  __shared__ __align__(16) float in_lds[IN_N];
  __shared__ __align__(16) float w_lds[8 * 9 * WSTR];
  __shared__ __align__(16) float wo_lds[15 * 64];

  // obj/delta weights for this block's 64 channels
  for (int l = tid; l < 960; l += 512) {
    int o = l >> 6, c = l & 63;
    int cg = cblk * 64 + c;
    wo_lds[l] = (o < 3) ? ow[o * 256 + cg] : dw[(o - 3) * 256 + cg];
  }

  float acc[PXT][8];
  #pragma unroll
  for (int j = 0; j < PXT; ++j)
    #pragma unroll
    for (int c = 0; c < 8; ++c) acc[j][c] = 0.f;

  const float* fbase = feat + (size_t)img * 256 * H * W;

  for (int c0 = 0; c0 < 256; c0 += 8) {
    __syncthreads();
    // stage input tile (+1 halo all around, zero padded)
    for (int l = tid; l < IN_N; l += 512) {
      int ci  = l / ROWSZ;
      int rem = l - ci * ROWSZ;
      int yy  = rem / SR, xx = rem - yy * SR;
      int gy = y0 - 1 + yy, gx = x0 - 1 + xx;
      float v = 0.f;
      if (gy >= 0 && gy < H && gx >= 0 && gx < W)
        v = fbase[((c0 + ci) * H + gy) * W + gx];
      in_lds[l] = v;
    }
    // stage weights: 4608 vals = 512 threads * 9 contiguous floats
    {
      int oc = tid >> 3, ci = tid & 7;
      const float* wp = cw + ((size_t)(cblk * 64 + oc) * 256 + (c0 + ci)) * 9;
      #pragma unroll
      for (int tap = 0; tap < 9; ++tap)
        w_lds[(ci * 9 + tap) * WSTR + oc] = wp[tap];
    }
    __syncthreads();
    for (int ci = 0; ci < 8; ++ci) {
      #pragma unroll
      for (int ky = 0; ky < 3; ++ky) {
        const float* row = &in_lds[(ci * (TH + 2) + py + ky) * SR + px];
        float win[4 * NR];
        #pragma unroll
        for (int rr = 0; rr < NR; ++rr) {
          float4 rv = *(const float4*)(row + 4 * rr);
          win[4*rr+0] = rv.x; win[4*rr+1] = rv.y;
          win[4*rr+2] = rv.z; win[4*rr+3] = rv.w;
        }
        #pragma unroll
        for (int kx = 0; kx < 3; ++kx) {
          const float* wb = &w_lds[(ci * 9 + ky * 3 + kx) * WSTR + tc * 8];
          float4 w0 = *(const float4*)wb;
          float4 w1 = *(const float4*)(wb + 4);
          #pragma unroll
          for (int j = 0; j < PXT; ++j) {
            float bv = win[j + kx];
            acc[j][0] = fmaf(bv, w0.x, acc[j][0]);
            acc[j][1] = fmaf(bv, w0.y, acc[j][1]);
            acc[j][2] = fmaf(bv, w0.z, acc[j][2]);
            acc[j][3] = fmaf(bv, w0.w, acc[j][3]);
            acc[j][4] = fmaf(bv, w1.x, acc[j][4]);
            acc[j][5] = fmaf(bv, w1.y, acc[j][5]);
            acc[j][6] = fmaf(bv, w1.z, acc[j][6]);
            acc[j][7] = fmaf(bv, w1.w, acc[j][7]);
          }
        }
      }
    }
  }

  // epilogue: t = relu(acc + bias); partial obj/delta dots over 64 ch
  float tv[PXT][8];
  #pragma unroll
  for (int c = 0; c < 8; ++c) {
    float b = cbias[cblk * 64 + tc * 8 + c];
    #pragma unroll
    for (int j = 0; j < PXT; ++j) tv[j][c] = fmaxf(acc[j][c] + b, 0.f);
  }
  const int gy = y0 + py;
  const int gx0 = x0 + px;
  const size_t pbase = (size_t)cblk * PS +
      ((size_t)img * PIX_TOTAL + px_base + gy * W + gx0) * 15;
  for (int o = 0; o < 15; ++o) {
    const float* wb = &wo_lds[o * 64 + tc * 8];
    float4 w0 = *(const float4*)wb;
    float4 w1 = *(const float4*)(wb + 4);
    float s[PXT];
    #pragma unroll
    for (int j = 0; j < PXT; ++j)
      s[j] = tv[j][0]*w0.x + tv[j][1]*w0.y + tv[j][2]*w0.z + tv[j][3]*w0.w
           + tv[j][4]*w1.x + tv[j][5]*w1.y + tv[j][6]*w1.z + tv[j][7]*w1.w;
    #pragma unroll
    for (int m = 1; m < 8; m <<= 1) {
      #pragma unroll
      for (int j = 0; j < PXT; ++j) s[j] += __shfl_xor(s[j], m, 64);
    }
    if (tc == 0) {
      #pragma unroll
      for (int j = 0; j < PXT; ++j)
        partial[pbase + (size_t)j * 15 + o] = s[j];
    }
  }
}

// ---------------------------------------------------------------------------
// Kernel 2: deterministic reduce of 4 channel-block partials + bias.
// ---------------------------------------------------------------------------
__global__ void __launch_bounds__(256)
reduce_kernel(const float* __restrict__ partial, const float* __restrict__ ob,
              const float* __restrict__ db, float* __restrict__ scores,
              float* __restrict__ deltas)
{
  int v = blockIdx.x * 256 + threadIdx.x;
  if (v >= PS) return;
  float s = ((partial[v] + partial[(size_t)PS + v]) + partial[(size_t)2 * PS + v])
            + partial[(size_t)3 * PS + v];
  int o = v % 15;
  int pv = v / 15;                       // img*PIX_TOTAL + pixel
  if (o < 3) {
    scores[(size_t)pv * 3 + o] = s + ob[o];
  } else {
    int c = o - 3;                       // a*4 + d
    deltas[((size_t)pv * 3 + (c >> 2)) * 4 + (c & 3)] = s + db[c];
  }
}

// ---------------------------------------------------------------------------
// Kernel 3: per-(img,lvl) exact top-k (radix select on monotone bits, tie
// break = lowest anchor index, matching jax.lax.top_k), then bitonic sort
// by (score desc, idx asc).
// ---------------------------------------------------------------------------
__global__ void __launch_bounds__(1024)
topk_kernel(const float* __restrict__ scores, float* __restrict__ sel_s,
            unsigned* __restrict__ sel_i)
{
  const int tid = threadIdx.x;
  const int bid = blockIdx.x;            // img*5 + lvl
  const int img = bid / 5, lvl = bid % 5;
  const int W = 256 >> lvl;
  const int N = W * W * 3;
  const int k = N < 1000 ? N : 1000;
  const float* sc = scores + (size_t)img * ATOT + (size_t)lvl_pxb(lvl) * 3;

  __shared__ unsigned hist[256];
  __shared__ unsigned sh_pref, sh_want;
  __shared__ int cnt_gt, cnt_tie;
  __shared__ float ss[1024];
  __shared__ unsigned si[1024];
  __shared__ unsigned ties[2048];

  unsigned prefix = 0; unsigned want = (unsigned)k;
  for (int pass = 0; pass < 4; ++pass) {
    const int shift = 24 - 8 * pass;
    if (tid < 256) hist[tid] = 0;
    __syncthreads();
    for (int i = tid; i < N; i += 1024) {
      unsigned u = fmono(sc[i]);
      if (pass == 0 || (u >> (shift + 8)) == prefix)
        atomicAdd(&hist[(u >> shift) & 255u], 1u);
    }
    __syncthreads();
    if (tid == 0) {
      unsigned cum = 0; int b = 255;
      for (; b > 0; --b) {
        if (cum + hist[b] >= want) break;
        cum += hist[b];
      }
      sh_pref = (prefix << 8) | (unsigned)b;
      sh_want = want - cum;
    }
    __syncthreads();
    prefix = sh_pref; want = sh_want;
    __syncthreads();
  }
  const unsigned T = prefix;             // exact 32-bit k-th key

  ss[tid] = -3e38f; si[tid] = 0xFFFFFFFFu;
  if (tid == 0) { cnt_gt = 0; cnt_tie = 0; }
  __syncthreads();
  for (int i = tid; i < N; i += 1024) {
    float f = sc[i];
    unsigned u = fmono(f);
    if (u > T) {
      int pos = atomicAdd(&cnt_gt, 1);
      ss[pos] = f; si[pos] = (unsigned)i;
    } else if (u == T) {
      int pos = atomicAdd(&cnt_tie, 1);
      if (pos < 2048) ties[pos] = (unsigned)i;
    }
  }
  __syncthreads();
  const int cg = cnt_gt;
  int need = k - cg;
  const int tn = cnt_tie < 2048 ? cnt_tie : 2048;
  if (need > tn) need = tn;              // pathological overflow guard
  for (int e = tid; e < tn; e += 1024) {
    unsigned mye = ties[e];
    int rank = 0;
    for (int j = 0; j < tn; ++j) rank += (ties[j] < mye) ? 1 : 0;
    if (rank < need) { ss[cg + rank] = sc[mye]; si[cg + rank] = mye; }
  }
  __syncthreads();
  // bitonic sort, descending by (score, idx asc); composite keys unique
  for (int k2 = 2; k2 <= 1024; k2 <<= 1) {
    for (int j2 = k2 >> 1; j2 > 0; j2 >>= 1) {
      int l2 = tid ^ j2;
      if (l2 > tid) {
        float a = ss[tid], b = ss[l2];
        unsigned ia = si[tid], ib = si[l2];
        bool less = (a < b) || (a == b && ia > ib);
        bool up = ((tid & k2) == 0);
        if (less == up) { ss[tid] = b; ss[l2] = a; si[tid] = ib; si[l2] = ia; }
      }
      __syncthreads();
    }
  }
  sel_s[(size_t)bid * 1024 + tid] = ss[tid];
  sel_i[(size_t)bid * 1024 + tid] = si[tid];
}

// ---------------------------------------------------------------------------
// Kernel 4: anchor + delta decode + clip (contraction-free to match numpy),
// raw boxes for output, offset boxes (+lvl*4096, quantizing!) for NMS.
// ---------------------------------------------------------------------------
__global__ void __launch_bounds__(256)
decode_kernel(const unsigned* __restrict__ sel_i, const float* __restrict__ deltas,
              float* __restrict__ braw, float* __restrict__ boff)
{
  int g = blockIdx.x * 256 + threadIdx.x;
  if (g >= 10240) return;
  int bid = g >> 10, r = g & 1023;
  int img = bid / 5, lvl = bid % 5;
  int W = 256 >> lvl, N = W * W * 3;
  int k = N < 1000 ? N : 1000;
  if (r >= k) return;
  unsigned idx = sel_i[(size_t)bid * 1024 + r];
  float obx[4] = {0.f, 0.f, 0.f, 0.f};
  if (idx < (unsigned)N) {
    int a = idx % 3;
    int pix = idx / 3;
    int x = pix % W, y = pix / W;
    float ar = (a == 0) ? 0.5f : (a == 1 ? 1.0f : 2.0f);
    float sz = (float)(32 << lvl);
    float stridef = (float)(4 << lvl);
    float wa0 = __fdiv_rn(sz, __fsqrt_rn(ar));
    float ha0 = __fmul_rn(wa0, ar);
    float sx = __fmul_rn((float)x, stridef);   // exact
    float sy = __fmul_rn((float)y, stridef);
    float x1a = __fadd_rn(sx, -0.5f * wa0);
    float y1a = __fadd_rn(sy, -0.5f * ha0);
    float x2a = __fadd_rn(sx,  0.5f * wa0);
    float y2a = __fadd_rn(sy,  0.5f * ha0);
    float wa  = __fsub_rn(x2a, x1a);
    float ha  = __fsub_rn(y2a, y1a);
    float cxa = __fadd_rn(x1a, __fmul_rn(0.5f, wa));
    float cya = __fadd_rn(y1a, __fmul_rn(0.5f, ha));
    const float* dl = deltas + ((size_t)img * ATOT + (size_t)lvl_pxb(lvl) * 3 + idx) * 4;
    float dx = dl[0], dy = dl[1];
    float dwv = fminf(dl[2], SCALE_CLAMP);
    float dhv = fminf(dl[3], SCALE_CLAMP);
    float cx = __fadd_rn(__fmul_rn(dx, wa), cxa);
    float cy = __fadd_rn(__fmul_rn(dy, ha), cya);
    float wb = __fmul_rn(expf(dwv), wa);
    float hb = __fmul_rn(expf(dhv), ha);
    obx[0] = fminf(fmaxf(__fsub_rn(cx, __fmul_rn(0.5f, wb)), 0.f), 1024.f);
    obx[1] = fminf(fmaxf(__fsub_rn(cy, __fmul_rn(0.5f, hb)), 0.f), 1024.f);
    obx[2] = fminf(fmaxf(__fadd_rn(cx, __fmul_rn(0.5f, wb)), 0.f), 1024.f);
    obx[3] = fminf(fmaxf(__fadd_rn(cy, __fmul_rn(0.5f, hb)), 0.f), 1024.f);
  }
  float loff = (float)lvl * 4096.0f;
  size_t o = ((size_t)bid * 1024 + r) * 4;
  braw[o + 0] = obx[0]; braw[o + 1] = obx[1];
  braw[o + 2] = obx[2]; braw[o + 3] = obx[3];
  boff[o + 0] = __fadd_rn(obx[0], loff); boff[o + 1] = __fadd_rn(obx[1], loff);
  boff[o + 2] = __fadd_rn(obx[2], loff); boff[o + 3] = __fadd_rn(obx[3], loff);
}

// ---------------------------------------------------------------------------
// Kernel 5: bitmask greedy NMS, one block per (img,lvl).
// Phase A: all pairwise IoU>thresh bits (j>i only) into LDS masks [k][NW].
// Phase B: single-wave serial scan (no barriers): if i alive, OR row i into
// the running suppressed bitmask. Exactly replicates the reference fori_loop
// (sup |= (~sup[i]) & (iou>T) & (idx>i)). IoU arithmetic bit-identical.
// LDS: 128000 (masks) + 16256 (boxes f4, padded) + 4064 (areas) ~= 148 KB.
// Padding (j + (j>>6)) breaks the 16-way bank conflict from j-stride-64.
// ---------------------------------------------------------------------------
#define BBI(j) ((j) + ((j) >> 6))
__global__ void __launch_bounds__(1024)
nms_fused(const float* __restrict__ boff, unsigned* __restrict__ sup_out)
{
  const int bid = blockIdx.x;            // img*5 + lvl
  const int lvl = bid % 5;
  const int W = 256 >> lvl;
  const int N = W * W * 3;
  const int k = N < 1000 ? N : 1000;
  const int tid = threadIdx.x;

  __shared__ __align__(16) float4 bb[1016];
  __shared__ float ba[1016];
  __shared__ unsigned long long masks[1000 * NW];
  __shared__ unsigned long long supw_sh[NW];

  for (int i = tid; i < k; i += 1024) {
    const float* b = boff + ((size_t)bid * 1024 + i) * 4;
    float4 v = {b[0], b[1], b[2], b[3]};
    bb[BBI(i)] = v;
    ba[BBI(i)] = __fmul_rn(__fsub_rn(v.z, v.x), __fsub_rn(v.w, v.y));
  }
  __syncthreads();

  // Phase A: mask words. t -> (i = t/16, w = t%16); word w covers j in
  // [64w, 64w+64); only j>i and j<k contribute.
  for (int t = tid; t < k * NW; t += 1024) {
    int i = t >> 4;
    int w = t & 15;
    unsigned long long m = 0ull;
    int j0 = w << 6;
    if (j0 + 63 > i) {
      float4 vi = bb[BBI(i)];
      float ai = ba[BBI(i)];
      int jend = (j0 + 64 < k) ? j0 + 64 : k;
      int js = (j0 > i + 1) ? j0 : i + 1;
      for (int j = js; j < jend; ++j) {
        float4 vj = bb[BBI(j)];
        float lx = fmaxf(vi.x, vj.x);
        float ly = fmaxf(vi.y, vj.y);
        float rx = fminf(vi.z, vj.z);
        float ry = fminf(vi.w, vj.w);
        float w2 = fmaxf(__fsub_rn(rx, lx), 0.f);
        float h2 = fmaxf(__fsub_rn(ry, ly), 0.f);
        float inter = __fmul_rn(w2, h2);
        float den = __fadd_rn(__fsub_rn(__fadd_rn(ai, ba[BBI(j)]), inter), 1e-9f);
        if (__fdiv_rn(inter, den) > 0.7f) m |= 1ull << (j - j0);
      }
    }
    masks[t] = m;
  }
  __syncthreads();

  // Phase B: one-wave greedy scan with 1-deep LDS prefetch.
  if (tid < 64) {
    const int lane = tid;
    const int ml = (lane < NW) ? lane : 0;
    unsigned long long supw = 0ull;
    unsigned long long mcur = masks[ml];           // row 0
    for (int i = 0; i < k; ++i) {
      int inext = (i + 1 < k) ? i + 1 : i;
      unsigned long long mnext = masks[inext * NW + ml];  // prefetch
      int wi = i >> 6;
      unsigned long long wv = __shfl(supw, wi, 64);
      if (((wv >> (i & 63)) & 1ull) == 0ull && lane < NW)
        supw |= mcur;
      mcur = mnext;
    }
    if (lane < NW) supw_sh[lane] = supw;
  }
  __syncthreads();
  for (int i = tid; i < k; i += 1024)
    sup_out[(size_t)bid * 1024 + i] =
        (unsigned)((supw_sh[i >> 6] >> (i & 63)) & 1ull);
}

// ---------------------------------------------------------------------------
// Kernel 6: replicate top_k(masked, 1000) by rank counting over the 4768
// concatenated entries (ties: lower concat idx first == stable argsort).
// ---------------------------------------------------------------------------
__global__ void __launch_bounds__(1024)
merge_kernel(const float* __restrict__ sel_s, const unsigned* __restrict__ sup,
             const float* __restrict__ braw, float* __restrict__ out)
{
  const int img = blockIdx.x;
  const int tid = threadIdx.x;
  __shared__ float ms[MTOT];
  for (int e = tid; e < MTOT; e += 1024) {
    int lvl = e < 4000 ? e / 1000 : 4;
    int r = e - lvl * 1000;
    size_t p2 = (size_t)(img * 5 + lvl) * 1024 + r;
    ms[e] = sup[p2] ? -1e9f : sel_s[p2];
  }
  __syncthreads();
  for (int e = tid; e < MTOT; e += 1024) {
    float me = ms[e];
    int rank = 0;
    for (int j = 0; j < MTOT; ++j) {
      float mj = ms[j];
      rank += (mj > me || (mj == me && j < e)) ? 1 : 0;
    }
    if (rank < 1000) {
      int lvl = e < 4000 ? e / 1000 : 4;
      int r = e - lvl * 1000;
      const float* b = braw + ((size_t)(img * 5 + lvl) * 1024 + r) * 4;
      float* o = out + ((size_t)img * 1000 + rank) * 5;
      o[0] = b[0]; o[1] = b[1]; o[2] = b[2]; o[3] = b[3]; o[4] = me;
    }
  }
}

// ---------------------------------------------------------------------------
extern "C" void kernel_launch(void* const* d_in, const int* in_sizes, int n_in,
                              void* d_out, int out_size, void* d_ws, size_t ws_size,
                              hipStream_t stream)
{
  const float* f0 = (const float*)d_in[0];
  const float* f1 = (const float*)d_in[1];
  const float* f2 = (const float*)d_in[2];
  const float* f3 = (const float*)d_in[3];
  const float* f4 = (const float*)d_in[4];
  const float* cw = (const float*)d_in[5];
  const float* cb = (const float*)d_in[6];
  const float* ow = (const float*)d_in[7];
  const float* ob = (const float*)d_in[8];
  const float* dw = (const float*)d_in[9];
  const float* db = (const float*)d_in[10];
  float* out = (float*)d_out;

  float* ws       = (float*)d_ws;
  float* partial  = ws;                              // 4*PS = 10,475,520 f
  float* scores   = ws + (size_t)4 * PS;             // 2*ATOT = 523,776 f
  float* deltas   = scores + (size_t)2 * ATOT;       // 8*ATOT = 2,095,104 f
  float* sel_s    = deltas + (size_t)8 * ATOT;       // 10,240 f
  unsigned* sel_i = (unsigned*)(sel_s + 10240);      // 10,240 u32
  float* braw     = (float*)(sel_i + 10240);         // 40,960 f
  float* boff     = braw + 40960;                    // 40,960 f
  unsigned* sup   = (unsigned*)(boff + 40960);       // 10,240 u32

  conv3_fused<128, 4, 8><<<dim3(128, 4, 2), 512, 0, stream>>>(f0, cw, cb, ow, dw, partial, 256, 256, 0);
  conv3_fused<128, 4, 8><<<dim3( 32, 4, 2), 512, 0, stream>>>(f1, cw, cb, ow, dw, partial, 128, 128, 65536);
  conv3_fused< 64, 8, 8><<<dim3(  8, 4, 2), 512, 0, stream>>>(f2, cw, cb, ow, dw, partial,  64,  64, 81920);
  conv3_fused< 32,16, 8><<<dim3(  2, 4, 2), 512, 0, stream>>>(f3, cw, cb, ow, dw, partial,  32,  32, 86016);
  conv3_fused< 16,16, 4><<<dim3(  1, 4, 2), 512, 0, stream>>>(f4, cw, cb, ow, dw, partial,  16,  16, 87040);
  reduce_kernel<<<PS / 256, 256, 0, stream>>>(partial, ob, db, scores, deltas);
  topk_kernel<<<10, 1024, 0, stream>>>(scores, sel_s, sel_i);
  decode_kernel<<<40, 256, 0, stream>>>(sel_i, deltas, braw, boff);
  nms_fused<<<10, 1024, 0, stream>>>(boff, sup);
  merge_kernel<<<2, 1024, 0, stream>>>(sel_s, sup, braw, out);
}